// Round 5
// baseline (89.129 us; speedup 1.0000x reference)
//
#include <hip/hip_runtime.h>
#include <math.h>

#define IN_DIM 256       // reduction dim (k)
#define BM 64            // rows per block == lanes per wave
#define TN 8             // outputs per thread
#define NWAVES 4
#define BN (NWAVES * TN) // 32 outputs per block

typedef float v2f __attribute__((ext_vector_type(2)));

// y[n,o] = max_i (x[n,i] + a[o,i]) + bias[o]
// lane = row; wave covers TN output columns; a-values ride the scalar pipe
// (wave-uniform addresses -> s_load_dwordx8); adds as v2f -> v_pk_add_f32.
// LDS x-tile is XOR-swizzled: ds_read_b128 phase groups {8k..8k+7} hit all 8
// bank-groups exactly once (minimum-aliasing, ~12cyc per m134).
__global__ __launch_bounds__(256, 2) void maxplus_kernel(
    const float* __restrict__ x, const float* __restrict__ a,
    const float* __restrict__ bias, float* __restrict__ y,
    int N, int OUT) {
  __shared__ __align__(16) float xs[BM * IN_DIM];  // 64 KB, XOR-swizzled rows

  const int tid  = threadIdx.x;
  const int lane = tid & 63;
  const int w    = tid >> 6;
  const int rowBase = blockIdx.x * BM;

  // ---- stage x tile: global (coalesced float4) -> LDS (swizzled) ----
  // LDS row R, 16B-chunk position p holds global chunk (p ^ (R&7)) of row R.
  const float* xt = x + (size_t)rowBase * IN_DIM;
  #pragma unroll
  for (int j = 0; j < 16; ++j) {
    const int R = w * 16 + j;
    float4 v = *reinterpret_cast<const float4*>(xt + (size_t)R * IN_DIM + lane * 4);
    const int dstChunk = lane ^ (R & 7);
    *reinterpret_cast<float4*>(xs + R * IN_DIM + dstChunk * 4) = v;
  }

  // ---- wave-uniform a/bias bases (scalarize to s_load) ----
  const int wq    = __builtin_amdgcn_readfirstlane(w);
  const int oBase = blockIdx.y * BN + wq * TN;
  const float* __restrict__ ap = a + (size_t)oBase * IN_DIM;  // wave-uniform
  const float* __restrict__ bp = bias + oBase;                // wave-uniform

  // hoist bias into SGPRs before the hot loop (used only in epilogue)
  float bv[TN];
  #pragma unroll
  for (int j = 0; j < TN; ++j) bv[j] = bp[j];

  float acc[TN];
  #pragma unroll
  for (int j = 0; j < TN; ++j) acc[j] = -INFINITY;

  __syncthreads();

  const float* xrow = xs + lane * IN_DIM;
  const int swz = lane & 7;

  // 32 iterations; each consumes 8 floats of x (2 swizzled 16B chunks) and
  // 8 contiguous floats of each of the TN a-rows (one s_load_dwordx8 each).
  // unroll 2: bigger scheduling window so s_loads issue an iteration ahead.
  #pragma unroll 2
  for (int cc = 0; cc < IN_DIM / 8; ++cc) {
    const int c0 = 2 * cc, c1 = 2 * cc + 1;
    float4 xv0 = *reinterpret_cast<const float4*>(xrow + ((c0 ^ swz) << 2));
    float4 xv1 = *reinterpret_cast<const float4*>(xrow + ((c1 ^ swz) << 2));
    v2f x0lo = {xv0.x, xv0.y};
    v2f x0hi = {xv0.z, xv0.w};
    v2f x1lo = {xv1.x, xv1.y};
    v2f x1hi = {xv1.z, xv1.w};
    #pragma unroll
    for (int j = 0; j < TN; ++j) {
      // 32B contiguous, wave-uniform -> s_load_dwordx8; SGPR pairs feed pk_add
      const v2f* aj = reinterpret_cast<const v2f*>(ap + j * IN_DIM + cc * 8);
      v2f t0 = x0lo + aj[0];           // v_pk_add_f32
      v2f t1 = x0hi + aj[1];
      v2f t2 = x1lo + aj[2];
      v2f t3 = x1hi + aj[3];
      // 9-value max tree in exactly 4x v_max3_f32
      float m0 = fmaxf(fmaxf(t0.x, t0.y), t1.x);
      float m1 = fmaxf(fmaxf(t1.y, t2.x), t2.y);
      float m2 = fmaxf(fmaxf(t3.x, t3.y), m0);
      acc[j] = fmaxf(fmaxf(m2, m1), acc[j]);
    }
  }

  // ---- epilogue: + bias, float4 stores (row-major y) ----
  const int row = rowBase + lane;
  float* yp = y + (size_t)row * OUT + oBase;
  #pragma unroll
  for (int j = 0; j < TN; j += 4) {
    float4 o4;
    o4.x = acc[j + 0] + bv[j + 0];
    o4.y = acc[j + 1] + bv[j + 1];
    o4.z = acc[j + 2] + bv[j + 2];
    o4.w = acc[j + 3] + bv[j + 3];
    *reinterpret_cast<float4*>(yp + j) = o4;
  }
}

extern "C" void kernel_launch(void* const* d_in, const int* in_sizes, int n_in,
                              void* d_out, int out_size, void* d_ws, size_t ws_size,
                              hipStream_t stream) {
  const float* x    = (const float*)d_in[0];
  const float* a    = (const float*)d_in[1];
  const float* bias = (const float*)d_in[2];
  float* y = (float*)d_out;

  const int N   = in_sizes[0] / IN_DIM;  // 4096
  const int OUT = in_sizes[2];           // 256

  dim3 grid(N / BM, OUT / BN);           // (64, 8) = 512 blocks
  maxplus_kernel<<<grid, 256, 0, stream>>>(x, a, bias, y, N, OUT);
}